// Round 1
// 147.390 us; speedup vs baseline: 1.0392x; 1.0392x over previous
//
#include <hip/hip_runtime.h>

#define F_IN 128
#define CH   128

typedef __attribute__((ext_vector_type(8))) short bf16x8;
typedef __attribute__((ext_vector_type(4))) float f32x4;
typedef __attribute__((ext_vector_type(4))) unsigned u32x4;

// f32 -> bf16 round-to-nearest-even
static __device__ __forceinline__ ushort f2b(float f) {
  union { float f; unsigned u; } v; v.f = f;
  const unsigned u = v.u;
  return (ushort)((u + 0x7FFFu + ((u >> 16) & 1u)) >> 16);
}

// ---------------------------------------------------------------------------
// Phase 1 (fused): blocks [0, gemm_blocks) do XW = X @ W via bf16 MFMA.
//                  blocks [gemm_blocks, ...) do row_ptr[r] = lower_bound(edge_row, r).
// GEMM: 8 waves (512 thr), 128 rows/block, W^T staged in LDS (bf16, XOR-swizzled).
// mfma_f32_16x16x32_bf16 layouts (guide §3, m89-verified):
//   A frag: row = lane&15, k = (lane>>4)*8 + j
//   B frag: col = lane&15, k = (lane>>4)*8 + j
//   C/D   : col = lane&15, row = (lane>>4)*4 + reg
// ---------------------------------------------------------------------------
__global__ __launch_bounds__(512) void gemm_rowptr_fused(
    const float* __restrict__ x, const float* __restrict__ w,
    ushort* __restrict__ xwb,
    const int* __restrict__ edge_row, int* __restrict__ row_ptr,
    int n, int n_edges, int gemm_blocks) {
  __shared__ __align__(16) ushort Wt[F_IN * CH];  // W^T, swizzled, 32 KB
  const int t = threadIdx.x;

  if ((int)blockIdx.x >= gemm_blocks) {
    // ---- rowptr tail blocks: CSR offsets from sorted edge_row ----
    const int r = ((int)blockIdx.x - gemm_blocks) * 512 + t;
    if (r <= n) {
      int lo = 0, hi = n_edges;
      while (lo < hi) {
        const int mid = (lo + hi) >> 1;
        if (edge_row[mid] < r) lo = mid + 1; else hi = mid;
      }
      row_ptr[r] = lo;
    }
    return;
  }

  // ---- GEMM blocks ----
  // stage W^T as bf16 with XOR swizzle: byte ^= (col&7)<<4  (W reused -> normal loads)
  for (int i = t; i < (F_IN * CH) / 4; i += 512) {
    const int k  = i >> 5;          // 0..127
    const int n4 = (i & 31) << 2;   // 0,4,...,124
    const f32x4 wv = *(const f32x4*)&w[k * CH + n4];
#pragma unroll
    for (int q = 0; q < 4; ++q) {
      const int nn = n4 + q;
      const int byte = (nn * 256 + k * 2) ^ ((nn & 7) << 4);
      *(ushort*)((char*)Wt + byte) = f2b(wv[q]);
    }
  }
  __syncthreads();

  const int wave = t >> 6, lane = t & 63;
  const int R0   = blockIdx.x * 128 + wave * 16;
  const int arow = R0 + (lane & 15);
  const int kgrp = (lane >> 4) * 8;

  // A fragments (4 K-steps), converted f32->bf16 in-register.
  // x is read exactly once -> non-temporal loads (protect L2/L3 for the XW table).
  bf16x8 a[4];
#pragma unroll
  for (int s = 0; s < 4; ++s) {
    if (arow < n) {
      const f32x4 p0 = __builtin_nontemporal_load(
          (const f32x4*)&x[arow * F_IN + s * 32 + kgrp]);
      const f32x4 p1 = __builtin_nontemporal_load(
          (const f32x4*)&x[arow * F_IN + s * 32 + kgrp + 4]);
#pragma unroll
      for (int j = 0; j < 4; ++j) {
        a[s][j]     = (short)f2b(p0[j]);
        a[s][j + 4] = (short)f2b(p1[j]);
      }
    } else {
#pragma unroll
      for (int j = 0; j < 8; ++j) a[s][j] = (short)0;
    }
  }

  f32x4 acc[8];
#pragma unroll
  for (int t8 = 0; t8 < 8; ++t8) acc[t8] = (f32x4){0.f, 0.f, 0.f, 0.f};

#pragma unroll
  for (int t8 = 0; t8 < 8; ++t8) {
    const int col = t8 * 16 + (lane & 15);
#pragma unroll
    for (int s = 0; s < 4; ++s) {
      const int byte = (col * 256 + (s * 32 + kgrp) * 2) ^ ((col & 7) << 4);
      const bf16x8 b = *(const bf16x8*)((const char*)Wt + byte);
      acc[t8] = __builtin_amdgcn_mfma_f32_16x16x32_bf16(a[s], b, acc[t8], 0, 0, 0);
    }
  }

  // store XW as bf16 (normal stores: we WANT xwb resident in L2/L3 for spmm)
  const int r0 = R0 + (lane >> 4) * 4;
#pragma unroll
  for (int t8 = 0; t8 < 8; ++t8) {
    const int col = t8 * 16 + (lane & 15);
#pragma unroll
    for (int i = 0; i < 4; ++i) {
      const int rr = r0 + i;
      if (rr < n) xwb[rr * CH + col] = f2b(acc[t8][i]);
    }
  }
}

// ---------------------------------------------------------------------------
// Phase 2: SpMM, one wave per output row (CSR). No atomics, bias+ReLU fused.
// Wave split into 4 groups of 16 lanes; each group gathers one edge's full
// 256B XW row (uint4/lane). 16 edges/iter -> 4 independent gather chains in
// flight per lane (MLP). Edge metadata + out use non-temporal hints so the
// reused 25.6MB XW table keeps cache residency. Cross-group butterfly at end.
// ---------------------------------------------------------------------------
#define FMA8(U, V)                                                    \
  do {                                                                \
    acc[0] = fmaf((V), __uint_as_float((U)[0] << 16), acc[0]);        \
    acc[1] = fmaf((V), __uint_as_float((U)[0] & 0xFFFF0000u), acc[1]);\
    acc[2] = fmaf((V), __uint_as_float((U)[1] << 16), acc[2]);        \
    acc[3] = fmaf((V), __uint_as_float((U)[1] & 0xFFFF0000u), acc[3]);\
    acc[4] = fmaf((V), __uint_as_float((U)[2] << 16), acc[4]);        \
    acc[5] = fmaf((V), __uint_as_float((U)[2] & 0xFFFF0000u), acc[5]);\
    acc[6] = fmaf((V), __uint_as_float((U)[3] << 16), acc[6]);        \
    acc[7] = fmaf((V), __uint_as_float((U)[3] & 0xFFFF0000u), acc[7]);\
  } while (0)

__global__ __launch_bounds__(256) void spmm_rowwave(
    const ushort* __restrict__ xwb, const float* __restrict__ edge_val,
    const int* __restrict__ edge_col, const int* __restrict__ row_ptr,
    const float* __restrict__ bias, float* __restrict__ out, int n) {
  const int wid = (int)((blockIdx.x * blockDim.x + threadIdx.x) >> 6);
  if (wid >= n) return;
  const int lane = threadIdx.x & 63;
  const int g  = lane >> 4;   // edge group 0..3
  const int li = lane & 15;   // channel group: channels li*8 .. li*8+7
  const int start = row_ptr[wid], end = row_ptr[wid + 1];
  const u32x4* __restrict__ xw4 = (const u32x4*)xwb;  // 16 u32x4 per row

  float acc[8];
#pragma unroll
  for (int j = 0; j < 8; ++j) acc[j] = 0.f;

  for (int e0 = start; e0 < end; e0 += 16) {
    int   cc[4];
    float vv[4];
#pragma unroll
    for (int q = 0; q < 4; ++q) {
      const int e = e0 + q * 4 + g;
      if (e < end) {
        cc[q] = __builtin_nontemporal_load(edge_col + e);
        vv[q] = __builtin_nontemporal_load(edge_val + e);
      } else {
        cc[q] = 0;            // gathers a hot (cached) line; v=0 kills the FMA
        vv[q] = 0.f;
      }
    }
    // 4 independent gather chains in flight
    const u32x4 u0 = xw4[cc[0] * 16 + li];
    const u32x4 u1 = xw4[cc[1] * 16 + li];
    const u32x4 u2 = xw4[cc[2] * 16 + li];
    const u32x4 u3 = xw4[cc[3] * 16 + li];
    FMA8(u0, vv[0]);
    FMA8(u1, vv[1]);
    FMA8(u2, vv[2]);
    FMA8(u3, vv[3]);
  }

  // sum the 4 edge-groups' partials (lanes differing in bits 4,5)
#pragma unroll
  for (int j = 0; j < 8; ++j) {
    acc[j] += __shfl_xor(acc[j], 16);
    acc[j] += __shfl_xor(acc[j], 32);
  }

  if (g == 0) {
    const int c = li * 8;
    f32x4 o0, o1;
    o0[0] = fmaxf(acc[0] + bias[c + 0], 0.f);
    o0[1] = fmaxf(acc[1] + bias[c + 1], 0.f);
    o0[2] = fmaxf(acc[2] + bias[c + 2], 0.f);
    o0[3] = fmaxf(acc[3] + bias[c + 3], 0.f);
    o1[0] = fmaxf(acc[4] + bias[c + 4], 0.f);
    o1[1] = fmaxf(acc[5] + bias[c + 5], 0.f);
    o1[2] = fmaxf(acc[6] + bias[c + 6], 0.f);
    o1[3] = fmaxf(acc[7] + bias[c + 7], 0.f);
    __builtin_nontemporal_store(o0, (f32x4*)&out[wid * CH + c]);
    __builtin_nontemporal_store(o1, (f32x4*)&out[wid * CH + c + 4]);
  }
}

extern "C" void kernel_launch(void* const* d_in, const int* in_sizes, int n_in,
                              void* d_out, int out_size, void* d_ws, size_t ws_size,
                              hipStream_t stream) {
  const float* x        = (const float*)d_in[0];
  const float* kernel   = (const float*)d_in[1];
  const float* bias     = (const float*)d_in[2];
  const float* edge_val = (const float*)d_in[3];
  const int*   edge_row = (const int*)d_in[4];
  const int*   edge_col = (const int*)d_in[5];
  float* out = (float*)d_out;

  const int n       = in_sizes[0] / F_IN;   // 100000
  const int n_edges = in_sizes[3];          // 3200000

  // ws layout: [xwb: n*CH bf16 = 25.6 MB][row_ptr: (n+1) int]
  ushort* xwb    = (ushort*)d_ws;
  int*    rowptr = (int*)((char*)d_ws + (size_t)n * CH * sizeof(ushort));

  // Phase 1 (fused): XW = X @ W (bf16 MFMA) + CSR row_ptr in tail blocks
  const int GB = (n + 127) / 128;
  const int RB = (n + 1 + 511) / 512;
  gemm_rowptr_fused<<<GB + RB, 512, 0, stream>>>(x, kernel, xwb, edge_row,
                                                 rowptr, n, n_edges, GB);

  // Phase 2: SpMM + bias + ReLU (one wave per row, no atomics)
  spmm_rowwave<<<(n + 3) / 4, 256, 0, stream>>>(xwb, edge_val, edge_col,
                                                rowptr, bias, out, n);
}